// Round 7
// baseline (116.562 us; speedup 1.0000x reference)
//
#include <hip/hip_runtime.h>

// Soft decision tree DEPTH=8, 255 internal nodes (heap order), 256 leaves,
// 10 classes, B=131072, 32 feats. fp32 in/out.
//
// R7: the measured wall is DS wave-instruction throughput per CU (~25 cy/instr
// under 4-wave concurrency; R4 and R6 both sit at ~8.5k DS-instr/CU = ~90us).
// So: minimize DS instructions.
//  - Node params (thr/feats/leafc) read via SCALAR loads (K$, uniform indices;
//    h made uniform with readfirstlane) -> zero DS for node records.
//  - TWO rows per thread; s_x layout [feat][row] -> one ds_read_b64 gather
//    serves both rows of an eval. 128 b64 gathers/thread total.
//  - Class accumulation in 20 REGISTERS (10 classes x 2 rows) via uniform
//    switch on the s_loaded leaf class (scalar cmp/branch + 2 v_add) ->
//    no leaf LDS writes, no sort, no epilogue scans.
//  - T=2 tree-halves per row-pair (h in {0,1}, 4 depth-3 subtrees each,
//    +3 duplicated top evals); merged through a small LDS buffer once.
// DS/thread ~ 165 (was ~270 at 2x thread count) -> ~3.3x less DS per CU.
// LDS = 32768 (s_x) + 2*10240 (merge) = 53248 B -> 2 blocks/CU resident.
// Grid 512 blocks = 2 blocks/CU, 8 waves/CU.

#define NFEAT 32
#define NCLS  10
#define TPB   256
#define ROWS  256          // rows per block (128 pairs x T=2)
#define L2E   1.4426950408889634f

__device__ __forceinline__ float fexp2(float z) {
#if __has_builtin(__builtin_amdgcn_exp2f)
  return __builtin_amdgcn_exp2f(z);
#else
  return exp2f(z);
#endif
}
__device__ __forceinline__ float frcp(float z) {
#if __has_builtin(__builtin_amdgcn_rcpf)
  return __builtin_amdgcn_rcpf(z);
#else
  return 1.0f / z;
#endif
}

struct P2 { float a, b; };

// sigmoid(x-t) for two rows: e = exp2((t-x)*log2e); act = 1/(1+e)
// pr = p*act (right child), pl = p*(1-act) = pr*e (left child)
__device__ __forceinline__ void evaln(const float* sx,
                                      const float* __restrict__ thr,
                                      const int*   __restrict__ feats,
                                      int n, int r0, P2 p, P2& pl, P2& pr) {
  const float tn = thr[n];                       // s_load (uniform n)
  const int   f  = feats[n];                     // s_load
  const float2 xs = *(const float2*)&sx[(f << 8) + r0];  // ds_read_b64
  const float e0 = fexp2((tn - xs.x) * L2E);
  const float e1 = fexp2((tn - xs.y) * L2E);
  const float a0 = frcp(1.0f + e0);
  const float a1 = frcp(1.0f + e1);
  pr.a = p.a * a0; pr.b = p.b * a1;
  pl.a = pr.a * e0; pl.b = pr.b * e1;
}

// acc[c] += p, c is wave-uniform scalar -> s_cmp/s_cbranch dispatch, VALU adds
__device__ __forceinline__ void addc(P2* acc, int c, P2 p) {
  switch (c) {
    case 0: acc[0].a += p.a; acc[0].b += p.b; break;
    case 1: acc[1].a += p.a; acc[1].b += p.b; break;
    case 2: acc[2].a += p.a; acc[2].b += p.b; break;
    case 3: acc[3].a += p.a; acc[3].b += p.b; break;
    case 4: acc[4].a += p.a; acc[4].b += p.b; break;
    case 5: acc[5].a += p.a; acc[5].b += p.b; break;
    case 6: acc[6].a += p.a; acc[6].b += p.b; break;
    case 7: acc[7].a += p.a; acc[7].b += p.b; break;
    case 8: acc[8].a += p.a; acc[8].b += p.b; break;
    default: acc[9].a += p.a; acc[9].b += p.b; break;
  }
}

__global__ __launch_bounds__(TPB, 2)
void dt_kernel(const float* __restrict__ x,
               const float* __restrict__ thr,
               const int*   __restrict__ feats,
               const int*   __restrict__ leafc,
               float*       __restrict__ out) {
  __shared__ float s_x[NFEAT * ROWS];    // [feat][row], raw x
  __shared__ float s_m0[NCLS * ROWS];    // h=0 partial sums [cls][row]
  __shared__ float s_m1[NCLS * ROWS];    // h=1 partial sums [cls][row]

  const int t    = threadIdx.x;
  const int pair = t & 127;
  const int h    = __builtin_amdgcn_readfirstlane(t >> 7);  // uniform!
  const int r0   = 2 * pair;             // first of this thread's two rows

  // --- stage x: 2048 float4 coalesced loads, transposed LDS writes ---
  const float4* xg = (const float4*)x + (size_t)blockIdx.x * (ROWS * NFEAT / 4);
#pragma unroll
  for (int k = 0; k < 8; ++k) {
    const int i4 = k * TPB + t;          // 0..2047
    const float4 v = xg[i4];
    const int r  = i4 >> 3;              // local row 0..255
    const int c0 = (i4 & 7) * 4;         // first of 4 feature columns
    s_x[(c0 + 0) * ROWS + r] = v.x;
    s_x[(c0 + 1) * ROWS + r] = v.y;
    s_x[(c0 + 2) * ROWS + r] = v.z;
    s_x[(c0 + 3) * ROWS + r] = v.w;
  }

  __syncthreads();

  // --- top of tree: 4 evals -> this thread's 4 depth-3 subtree probs ---
  P2 one{1.0f, 1.0f}, pl, pr;
  evaln(s_x, thr, feats, 0, r0, one, pl, pr);
  P2 pd1 = h ? pr : pl;                          // node 1+h
  evaln(s_x, thr, feats, 1 + h, r0, pd1, pl, pr);
  P2 pA = pl, pB = pr;                           // nodes 3+2h, 4+2h
  P2 ps0, ps1, ps2, ps3;
  evaln(s_x, thr, feats, 3 + 2 * h, r0, pA, ps0, ps1);  // subtrees 7+4h, 8+4h
  evaln(s_x, thr, feats, 4 + 2 * h, r0, pB, ps2, ps3);  // subtrees 9+4h, 10+4h

  // --- register class accumulators (10 classes x 2 rows) ---
  P2 acc[NCLS];
#pragma unroll
  for (int c = 0; c < NCLS; ++c) { acc[c].a = 0.0f; acc[c].b = 0.0f; }

  // --- 4 depth-3..7 subtrees, level-unrolled, uniform node indices ---
#pragma unroll 1
  for (int s = 0; s < 4; ++s) {
    const int m = 7 + 4 * h + s;                 // subtree root (depth 3)
    const int q = m - 7;                         // 0..7
    const P2 pS = (s & 2) ? ((s & 1) ? ps3 : ps2) : ((s & 1) ? ps1 : ps0);

    P2 p4[2], p5[4], p6[8], p7[16];
    evaln(s_x, thr, feats, m, r0, pS, p4[0], p4[1]);
#pragma unroll
    for (int j = 0; j < 2; ++j)
      evaln(s_x, thr, feats, 15 + 2 * q + j, r0, p4[j], p5[2 * j], p5[2 * j + 1]);
#pragma unroll
    for (int j = 0; j < 4; ++j)
      evaln(s_x, thr, feats, 31 + 4 * q + j, r0, p5[j], p6[2 * j], p6[2 * j + 1]);
#pragma unroll
    for (int j = 0; j < 8; ++j)
      evaln(s_x, thr, feats, 63 + 8 * q + j, r0, p6[j], p7[2 * j], p7[2 * j + 1]);
#pragma unroll
    for (int j = 0; j < 16; ++j) {
      P2 ll, lr;
      evaln(s_x, thr, feats, 127 + 16 * q + j, r0, p7[j], ll, lr);
      const int cL = leafc[32 * q + 2 * j];      // s_load, uniform
      const int cR = leafc[32 * q + 2 * j + 1];  // s_load, uniform
      addc(acc, cL, ll);                         // scalar-branch banking
      addc(acc, cR, lr);
    }
  }

  // --- merge the two tree-halves through LDS, then coalesced output ---
  float* sm = h ? s_m1 : s_m0;
#pragma unroll
  for (int c = 0; c < NCLS; ++c)
    *(float2*)&sm[c * ROWS + r0] = make_float2(acc[c].a, acc[c].b);

  __syncthreads();

  float* og = out + (size_t)blockIdx.x * (ROWS * NCLS);
#pragma unroll
  for (int k = 0; k < NCLS; ++k) {
    const int j = k * TPB + t;                   // 0..2559, coalesced
    const int r = j / NCLS;                      // magic-mul
    const int c = j - r * NCLS;
    og[j] = s_m0[c * ROWS + r] + s_m1[c * ROWS + r];
  }
}

extern "C" void kernel_launch(void* const* d_in, const int* in_sizes, int n_in,
                              void* d_out, int out_size, void* d_ws, size_t ws_size,
                              hipStream_t stream) {
  const float* x     = (const float*)d_in[0];
  const float* thr   = (const float*)d_in[1];
  const int*   feats = (const int*)d_in[2];
  const int*   leafc = (const int*)d_in[3];
  float*       out   = (float*)d_out;

  const int B    = in_sizes[0] / NFEAT;          // 131072
  const int grid = B / ROWS;                     // 512

  dt_kernel<<<grid, TPB, 0, stream>>>(x, thr, feats, leafc, out);
}

// Round 8
// 96.017 us; speedup vs baseline: 1.2140x; 1.2140x over previous
//
#include <hip/hip_runtime.h>

// Soft decision tree DEPTH=8, 255 internal nodes (heap order), 256 leaves,
// 10 classes, B=131072, 32 feats. fp32 in/out.
//
// R8. Measured facts so far (rocprof per-dispatch, bench carries ~59us fixed
// harness overhead): fp32 LDS atomics 183us; plain LDS RMW 27us (= DS
// single-issue limit, ~5.8cy/instr, 730 DS-instr/thread); R6 write-only+sort
// 31us; R7 register-switch 57us (scalar-branch serialization). Wall = DS
// instruction count; branches and fp32 RMW/atomics are forbidden.
//
// Design:
//  - setup_kernel (1 block): class-sorts the 256 leaves per pass-half into
//    d_ws: sp[256] (pass-relative slot 0..127), base/cnt[2][10].
//  - dt_kernel: 256 thr/block, 64 rows, 2 rows/thread (r0=2*(t&31)),
//    h=t>>5 owns depth-4 subtree q=h+8*pass (2 passes halve leafp to 32KB).
//    * x staged [feat][row] stride 65, pre-scaled by log2e: one ds_read_b64
//      serves both rows of an eval (~2-way conflicts).
//    * node records as LDS broadcasts: int2 b64 (d0..d6), int4 b128 (d7,
//      with BAKED sorted slots -> eval + both leaf slots in one DS op).
//    * leaf writes: ds_write_b64 (row-pair adjacent), write-only, no chains.
//    * epilogue: per (class,row) sum over the class's contiguous slot range,
//      4-way unrolled lane-linear b32 reads; accumulate in registers across
//      passes; single coalesced-ish global write.
// DS ~150 instr/thread. LDS = 32768(lp) + 8320(x) + 1016 + 2048 + 160
// = 44312 B -> 3 blocks/CU.

#define NFEAT 32
#define NCLS  10
#define TPB   256
#define ROWS  64
#define XS    65           // padded stride for s_x -> ~2-way banks on b64 gather
#define L2E   1.4426950408889634f

__device__ __forceinline__ float fexp2(float z) {
#if __has_builtin(__builtin_amdgcn_exp2f)
  return __builtin_amdgcn_exp2f(z);
#else
  return exp2f(z);
#endif
}
__device__ __forceinline__ float frcp(float z) {
#if __has_builtin(__builtin_amdgcn_rcpf)
  return __builtin_amdgcn_rcpf(z);
#else
  return 1.0f / z;
#endif
}

struct P2 { float a, b; };

// --- setup: class-sort leaves within each half (pass) --------------------
// ws[0..255]   = sp[leaf]: pass-relative sorted slot (0..127)
// ws[256..275] = base[pass][class], ws[276..295] = cnt[pass][class]
__global__ void setup_kernel(const int* __restrict__ leafc, int* __restrict__ ws) {
  __shared__ unsigned cnt[2][16];
  __shared__ unsigned base[2][16];
  const int t = threadIdx.x;
  if (t < 32) cnt[t >> 4][t & 15] = 0u;
  __syncthreads();
  const int c = leafc[t];
  const int p = t >> 7;                       // leaves 0..127 pass0, 128..255 pass1
  const unsigned pos = atomicAdd(&cnt[p][c], 1u);   // native ds_add_rtn_u32
  __syncthreads();
  if (t < 2) {
    unsigned b = 0;
#pragma unroll
    for (int k = 0; k < NCLS; ++k) { base[t][k] = b; b += cnt[t][k]; }
  }
  __syncthreads();
  ws[t] = (int)(base[p][c] + pos);
  if (t < 2 * NCLS) {
    const int pp = t / NCLS, cc = t - pp * NCLS;
    ws[256 + t]            = (int)base[pp][cc];
    ws[256 + 2 * NCLS + t] = (int)cnt[pp][cc];
  }
}

// sigmoid eval for two adjacent rows; e = exp2(t2 - x2) with log2e prefolded
__device__ __forceinline__ void evaln(const int2* nd, const float* sx,
                                      int n, int r0, P2 p, P2& pl, P2& pr) {
  const int2 r = nd[n];                                   // ds_read_b64 broadcast
  const float2 xs = *(const float2*)&sx[r.y * XS + r0];   // ds_read_b64 gather
  const float e0 = fexp2(__int_as_float(r.x) - xs.x);
  const float e1 = fexp2(__int_as_float(r.x) - xs.y);
  const float a0 = frcp(1.0f + e0);
  const float a1 = frcp(1.0f + e1);
  pr.a = p.a * a0; pr.b = p.b * a1;
  pl.a = pr.a * e0; pl.b = pr.b * e1;
}

__global__ __launch_bounds__(TPB, 3)
void dt_kernel(const float* __restrict__ x,
               const float* __restrict__ thr,
               const int*   __restrict__ feats,
               const int*   __restrict__ ws,
               float*       __restrict__ out) {
  __shared__ float s_lp[128 * ROWS];   // 32 KB, [slot][row], write-only hot loop
  __shared__ float s_x[NFEAT * XS];    // 8320 B, [feat][row] stride 65, *log2e
  __shared__ int2  s_nd[127];          // d0..d6 {thr*log2e, feat}
  __shared__ int4  s_nd7[128];         // d7 {thr*log2e, feat, slotL, slotR}
  __shared__ int   s_bc[4 * NCLS];     // base[2][10] then cnt[2][10]

  const int t  = threadIdx.x;
  const int r0 = 2 * (t & 31);         // this thread's row pair
  const int h  = t >> 5;               // 0..7: which depth-4 subtree (per pass)

  // --- stage x: coalesced float4 reads, transposed padded LDS writes ---
  const float4* xg = (const float4*)x + (size_t)blockIdx.x * (ROWS * NFEAT / 4);
#pragma unroll
  for (int k = 0; k < 2; ++k) {
    const int i4 = k * TPB + t;        // 0..511
    const float4 v = xg[i4];
    const int r  = i4 >> 3;            // local row 0..63
    const int c0 = (i4 & 7) * 4;
    s_x[(c0 + 0) * XS + r] = v.x * L2E;
    s_x[(c0 + 1) * XS + r] = v.y * L2E;
    s_x[(c0 + 2) * XS + r] = v.z * L2E;
    s_x[(c0 + 3) * XS + r] = v.w * L2E;
  }
  // --- stage node records; bake sorted slots into depth-7 int4 ---
  if (t < 127) {
    s_nd[t] = make_int2(__float_as_int(thr[t] * L2E), feats[t]);
  }
  if (t >= 128) {
    const int n7 = t - 128;            // 0..127; node 127+n7; leaves 2n7, 2n7+1
    const int2 spp = ((const int2*)ws)[n7];
    s_nd7[n7] = make_int4(__float_as_int(thr[127 + n7] * L2E), feats[127 + n7],
                          spp.x, spp.y);
  }
  if (t < 4 * NCLS) s_bc[t] = ws[256 + t];

  __syncthreads();

  // --- root eval once; reused by both passes ---
  P2 pl, pr, rootL, rootR;
  evaln(s_nd, s_x, 0, r0, P2{1.0f, 1.0f}, rootL, rootR);

  float accv0 = 0.0f, accv1 = 0.0f, accv2 = 0.0f;

#pragma unroll 1
  for (int pass = 0; pass < 2; ++pass) {
    const int q = h + 8 * pass;        // depth-4 subtree index 0..15

    // path: node 1+pass -> 3+(q>>2) -> 7+(q>>1) -> subtree prob of node 15+q
    P2 pd1 = pass ? rootR : rootL;
    evaln(s_nd, s_x, 1 + pass, r0, pd1, pl, pr);
    P2 pd2 = ((q >> 2) & 1) ? pr : pl;
    evaln(s_nd, s_x, 3 + (q >> 2), r0, pd2, pl, pr);
    P2 pd3 = ((q >> 1) & 1) ? pr : pl;
    evaln(s_nd, s_x, 7 + (q >> 1), r0, pd3, pl, pr);
    P2 pd4 = (q & 1) ? pr : pl;

    // depth-4..7 subtree: 1+2+4 internal evals + 8 leaf-pair evals
    P2 p5[2], p6[4], p7[8];
    evaln(s_nd, s_x, 15 + q, r0, pd4, p5[0], p5[1]);
#pragma unroll
    for (int j = 0; j < 2; ++j)
      evaln(s_nd, s_x, 31 + 2 * q + j, r0, p5[j], p6[2 * j], p6[2 * j + 1]);
#pragma unroll
    for (int j = 0; j < 4; ++j)
      evaln(s_nd, s_x, 63 + 4 * q + j, r0, p6[j], p7[2 * j], p7[2 * j + 1]);
#pragma unroll
    for (int j = 0; j < 8; ++j) {
      const int4 r = s_nd7[8 * q + j];                     // b128 broadcast
      const float2 xs = *(const float2*)&s_x[r.y * XS + r0];
      const float e0 = fexp2(__int_as_float(r.x) - xs.x);
      const float e1 = fexp2(__int_as_float(r.x) - xs.y);
      const float a0 = frcp(1.0f + e0);
      const float a1 = frcp(1.0f + e1);
      const float ra = p7[j].a * a0, rb = p7[j].b * a1;    // right-leaf probs
      const float la = ra * e0,      lb = rb * e1;         // left-leaf probs
      *(float2*)&s_lp[r.z * ROWS + r0] = make_float2(la, lb);  // ds_write_b64
      *(float2*)&s_lp[r.w * ROWS + r0] = make_float2(ra, rb);
    }

    __syncthreads();                   // leafp complete for this pass

    // --- epilogue: 640 (class,row) tasks over 256 threads ---
#pragma unroll
    for (int k = 0; k < 3; ++k) {
      const int j = k * TPB + t;
      if (j < ROWS * NCLS) {
        const int rr  = j & (ROWS - 1);
        const int cix = j >> 6;        // wave-uniform
        const int s0 = __builtin_amdgcn_readfirstlane(s_bc[pass * NCLS + cix]);
        const int n  = __builtin_amdgcn_readfirstlane(s_bc[2 * NCLS + pass * NCLS + cix]);
        float a0 = 0.f, a1 = 0.f, a2 = 0.f, a3 = 0.f;
        int i = 0;
        for (; i + 4 <= n; i += 4) {   // 4 independent lane-linear b32 reads
          a0 += s_lp[(s0 + i + 0) * ROWS + rr];
          a1 += s_lp[(s0 + i + 1) * ROWS + rr];
          a2 += s_lp[(s0 + i + 2) * ROWS + rr];
          a3 += s_lp[(s0 + i + 3) * ROWS + rr];
        }
        for (; i < n; ++i) a0 += s_lp[(s0 + i) * ROWS + rr];
        const float a = (a0 + a1) + (a2 + a3);
        if (k == 0) accv0 += a; else if (k == 1) accv1 += a; else accv2 += a;
      }
    }

    __syncthreads();                   // reads done before next pass overwrites
  }

  // --- output ---
  float* og = out + (size_t)blockIdx.x * (ROWS * NCLS);
#pragma unroll
  for (int k = 0; k < 3; ++k) {
    const int j = k * TPB + t;
    if (j < ROWS * NCLS) {
      const float a = (k == 0) ? accv0 : (k == 1) ? accv1 : accv2;
      og[(j & (ROWS - 1)) * NCLS + (j >> 6)] = a;
    }
  }
}

extern "C" void kernel_launch(void* const* d_in, const int* in_sizes, int n_in,
                              void* d_out, int out_size, void* d_ws, size_t ws_size,
                              hipStream_t stream) {
  const float* x     = (const float*)d_in[0];
  const float* thr   = (const float*)d_in[1];
  const int*   feats = (const int*)d_in[2];
  const int*   leafc = (const int*)d_in[3];
  float*       out   = (float*)d_out;
  int*         ws    = (int*)d_ws;

  const int B    = in_sizes[0] / NFEAT;    // 131072
  const int grid = B / ROWS;               // 2048

  setup_kernel<<<1, 256, 0, stream>>>(leafc, ws);
  dt_kernel<<<grid, TPB, 0, stream>>>(x, thr, feats, ws, out);
}

// Round 9
// 91.902 us; speedup vs baseline: 1.2683x; 1.0448x over previous
//
#include <hip/hip_runtime.h>

// Soft decision tree DEPTH=8, 255 internal nodes (heap order), 256 leaves,
// 10 classes, B=131072, 32 feats. fp32 in/out.
//
// R9. Measured (bench minus ~59us fixed harness overhead): R4 plain-RMW 27us
// (16 waves/CU), R6 31us, R8 ~33us (12 waves/CU) despite 3.5x fewer DS instrs
// -> DS *throughput* models under-predict by ~3x; hypothesis: latency-bound at
// 3 waves/SIMD. This round: raise residency to 5 blocks/CU (20 waves/CU) by
// cutting LDS 44.3 -> 27.9 KB, and halve epilogue DS reads:
//  - s_lp holds leaf probs in BF16, two rows packed per u32 (16 KB instead of
//    32 KB fp32): leaf writes are b32, epilogue b32 reads carry 2 rows,
//    unpack is shl/and + add (VALU idle at 5%). RTNE packing; class-sum
//    error <= sum(p)*2^-9 ~ 2e-3, well under the 9.375e-3 threshold.
//  - everything else structurally R8: setup kernel class-sorts leaves and
//    bakes slots into depth-7 int4 records; [feat][row] stride-65 x-tile,
//    one b64 gather serves a row pair; 2 passes over 128-slot halves.
// LDS = 16384(lp) + 8320(x) + 1016(nd) + 2048(nd7) + 160(bc) = 27928 B
//   -> 5 blocks/CU. __launch_bounds__(256,5) caps VGPR at 96 (R8 used 68).

#define NFEAT 32
#define NCLS  10
#define TPB   256
#define ROWS  64
#define RPRS  32           // row pairs
#define XS    65           // padded stride for s_x
#define L2E   1.4426950408889634f

__device__ __forceinline__ float fexp2(float z) {
#if __has_builtin(__builtin_amdgcn_exp2f)
  return __builtin_amdgcn_exp2f(z);
#else
  return exp2f(z);
#endif
}
__device__ __forceinline__ float frcp(float z) {
#if __has_builtin(__builtin_amdgcn_rcpf)
  return __builtin_amdgcn_rcpf(z);
#else
  return 1.0f / z;
#endif
}

struct P2 { float a, b; };

// pack two fp32 (in [0,1]) as bf16 pair, RTNE-ish (round half up + parity)
__device__ __forceinline__ unsigned packbf(float lo, float hi) {
  unsigned ul = __float_as_uint(lo);
  unsigned uh = __float_as_uint(hi);
  ul = (ul + 0x7fffu + ((ul >> 16) & 1u)) >> 16;
  uh = (uh + 0x7fffu + ((uh >> 16) & 1u)) & 0xffff0000u;
  return ul | uh;
}

// --- setup: class-sort leaves within each half (pass) --------------------
// ws[0..255]   = sp[leaf]: pass-relative sorted slot (0..127)
// ws[256..275] = base[pass][class], ws[276..295] = cnt[pass][class]
__global__ void setup_kernel(const int* __restrict__ leafc, int* __restrict__ ws) {
  __shared__ unsigned cnt[2][16];
  __shared__ unsigned base[2][16];
  const int t = threadIdx.x;
  if (t < 32) cnt[t >> 4][t & 15] = 0u;
  __syncthreads();
  const int c = leafc[t];
  const int p = t >> 7;
  const unsigned pos = atomicAdd(&cnt[p][c], 1u);   // native ds_add_rtn_u32
  __syncthreads();
  if (t < 2) {
    unsigned b = 0;
#pragma unroll
    for (int k = 0; k < NCLS; ++k) { base[t][k] = b; b += cnt[t][k]; }
  }
  __syncthreads();
  ws[t] = (int)(base[p][c] + pos);
  if (t < 2 * NCLS) {
    const int pp = t / NCLS, cc = t - pp * NCLS;
    ws[256 + t]            = (int)base[pp][cc];
    ws[256 + 2 * NCLS + t] = (int)cnt[pp][cc];
  }
}

// sigmoid eval for two adjacent rows; log2e prefolded into node + x
__device__ __forceinline__ void evaln(const int2* nd, const float* sx,
                                      int n, int r0, P2 p, P2& pl, P2& pr) {
  const int2 r = nd[n];                                   // ds_read_b64 broadcast
  const float2 xs = *(const float2*)&sx[r.y * XS + r0];   // ds_read_b64 gather
  const float e0 = fexp2(__int_as_float(r.x) - xs.x);
  const float e1 = fexp2(__int_as_float(r.x) - xs.y);
  const float a0 = frcp(1.0f + e0);
  const float a1 = frcp(1.0f + e1);
  pr.a = p.a * a0; pr.b = p.b * a1;
  pl.a = pr.a * e0; pl.b = pr.b * e1;
}

__global__ __launch_bounds__(TPB, 5)
void dt_kernel(const float* __restrict__ x,
               const float* __restrict__ thr,
               const int*   __restrict__ feats,
               const int*   __restrict__ ws,
               float*       __restrict__ out) {
  __shared__ unsigned s_lp[128 * RPRS];  // 16 KB, [slot][rowpair], bf16x2
  __shared__ float    s_x[NFEAT * XS];   // 8320 B, [feat][row] stride 65, *log2e
  __shared__ int2     s_nd[127];         // d0..d6 {thr*log2e, feat}
  __shared__ int4     s_nd7[128];        // d7 {thr*log2e, feat, slotL, slotR}
  __shared__ int      s_bc[4 * NCLS];    // base[2][10] then cnt[2][10]

  const int t  = threadIdx.x;
  const int rp = t & (RPRS - 1);         // row pair 0..31
  const int r0 = 2 * rp;
  const int h  = t >> 5;                 // 0..7: depth-4 subtree (per pass)

  // --- stage x: coalesced float4 reads, transposed padded LDS writes ---
  const float4* xg = (const float4*)x + (size_t)blockIdx.x * (ROWS * NFEAT / 4);
#pragma unroll
  for (int k = 0; k < 2; ++k) {
    const int i4 = k * TPB + t;          // 0..511
    const float4 v = xg[i4];
    const int r  = i4 >> 3;              // local row 0..63
    const int c0 = (i4 & 7) * 4;
    s_x[(c0 + 0) * XS + r] = v.x * L2E;
    s_x[(c0 + 1) * XS + r] = v.y * L2E;
    s_x[(c0 + 2) * XS + r] = v.z * L2E;
    s_x[(c0 + 3) * XS + r] = v.w * L2E;
  }
  // --- stage node records; bake sorted slots into depth-7 int4 ---
  if (t < 127) {
    s_nd[t] = make_int2(__float_as_int(thr[t] * L2E), feats[t]);
  }
  if (t >= 128) {
    const int n7 = t - 128;              // node 127+n7; leaves 2n7, 2n7+1
    const int2 spp = ((const int2*)ws)[n7];
    s_nd7[n7] = make_int4(__float_as_int(thr[127 + n7] * L2E), feats[127 + n7],
                          spp.x, spp.y);
  }
  if (t < 4 * NCLS) s_bc[t] = ws[256 + t];

  __syncthreads();

  // --- root eval once; reused by both passes ---
  P2 pl, pr, rootL, rootR;
  evaln(s_nd, s_x, 0, r0, P2{1.0f, 1.0f}, rootL, rootR);

  // register accumulators across passes: task0 = (c=t>>5, rp), task1 (t<64)
  float aLo0 = 0.f, aHi0 = 0.f, aLo1 = 0.f, aHi1 = 0.f;

#pragma unroll 1
  for (int pass = 0; pass < 2; ++pass) {
    const int q = h + 8 * pass;          // depth-4 subtree index 0..15

    P2 pd1 = pass ? rootR : rootL;
    evaln(s_nd, s_x, 1 + pass, r0, pd1, pl, pr);
    P2 pd2 = ((q >> 2) & 1) ? pr : pl;
    evaln(s_nd, s_x, 3 + (q >> 2), r0, pd2, pl, pr);
    P2 pd3 = ((q >> 1) & 1) ? pr : pl;
    evaln(s_nd, s_x, 7 + (q >> 1), r0, pd3, pl, pr);
    P2 pd4 = (q & 1) ? pr : pl;

    // depth-4..7 subtree: 1+2+4 internal evals + 8 leaf-pair evals
    P2 p5[2], p6[4], p7[8];
    evaln(s_nd, s_x, 15 + q, r0, pd4, p5[0], p5[1]);
#pragma unroll
    for (int j = 0; j < 2; ++j)
      evaln(s_nd, s_x, 31 + 2 * q + j, r0, p5[j], p6[2 * j], p6[2 * j + 1]);
#pragma unroll
    for (int j = 0; j < 4; ++j)
      evaln(s_nd, s_x, 63 + 4 * q + j, r0, p6[j], p7[2 * j], p7[2 * j + 1]);
#pragma unroll
    for (int j = 0; j < 8; ++j) {
      const int4 r = s_nd7[8 * q + j];                   // b128 broadcast
      const float2 xs = *(const float2*)&s_x[r.y * XS + r0];
      const float e0 = fexp2(__int_as_float(r.x) - xs.x);
      const float e1 = fexp2(__int_as_float(r.x) - xs.y);
      const float a0 = frcp(1.0f + e0);
      const float a1 = frcp(1.0f + e1);
      const float ra = p7[j].a * a0, rb = p7[j].b * a1;  // right-leaf probs
      const float la = ra * e0,      lb = rb * e1;       // left-leaf probs
      s_lp[r.z * RPRS + rp] = packbf(la, lb);            // ds_write_b32
      s_lp[r.w * RPRS + rp] = packbf(ra, rb);
    }

    __syncthreads();                     // leafp complete for this pass

    // --- epilogue: 320 (class,rowpair) tasks; reads carry 2 rows each ---
#pragma unroll
    for (int rep = 0; rep < 2; ++rep) {
      const int j = rep * TPB + t;
      if (j < NCLS * RPRS) {
        const int jrp = j & (RPRS - 1);
        const int c   = j >> 5;          // uniform per half-wave
        const int s0 = s_bc[pass * NCLS + c];
        const int n  = s_bc[2 * NCLS + pass * NCLS + c];
        float l0 = 0.f, l1 = 0.f, h0 = 0.f, h1 = 0.f;
        int i = 0;
        for (; i + 2 <= n; i += 2) {     // independent b32 reads in flight
          const unsigned u0 = s_lp[(s0 + i + 0) * RPRS + jrp];
          const unsigned u1 = s_lp[(s0 + i + 1) * RPRS + jrp];
          l0 += __uint_as_float(u0 << 16);
          h0 += __uint_as_float(u0 & 0xffff0000u);
          l1 += __uint_as_float(u1 << 16);
          h1 += __uint_as_float(u1 & 0xffff0000u);
        }
        if (i < n) {
          const unsigned u0 = s_lp[(s0 + i) * RPRS + jrp];
          l0 += __uint_as_float(u0 << 16);
          h0 += __uint_as_float(u0 & 0xffff0000u);
        }
        if (rep == 0) { aLo0 += l0 + l1; aHi0 += h0 + h1; }
        else          { aLo1 += l0 + l1; aHi1 += h0 + h1; }
      }
    }

    __syncthreads();                     // reads done before next pass
  }

  // --- output: task (c, rp) owns rows 2rp, 2rp+1 of class c ---
  float* og = out + (size_t)blockIdx.x * (ROWS * NCLS);
  {
    const int c = t >> 5;
    og[(2 * rp) * NCLS + c]     = aLo0;
    og[(2 * rp + 1) * NCLS + c] = aHi0;
  }
  if (t < 64) {
    const int c = 8 + (t >> 5);
    og[(2 * rp) * NCLS + c]     = aLo1;
    og[(2 * rp + 1) * NCLS + c] = aHi1;
  }
}

extern "C" void kernel_launch(void* const* d_in, const int* in_sizes, int n_in,
                              void* d_out, int out_size, void* d_ws, size_t ws_size,
                              hipStream_t stream) {
  const float* x     = (const float*)d_in[0];
  const float* thr   = (const float*)d_in[1];
  const int*   feats = (const int*)d_in[2];
  const int*   leafc = (const int*)d_in[3];
  float*       out   = (float*)d_out;
  int*         ws    = (int*)d_ws;

  const int B    = in_sizes[0] / NFEAT;    // 131072
  const int grid = B / ROWS;               // 2048

  setup_kernel<<<1, 256, 0, stream>>>(leafc, ws);
  dt_kernel<<<grid, TPB, 0, stream>>>(x, thr, feats, ws, out);
}